// Round 1
// baseline (115.749 us; speedup 1.0000x reference)
//
#include <hip/hip_runtime.h>
#include <hip/hip_bf16.h>
#include <math.h>

// Problem: B=4, L=2048 (M = 8192 rows), D_MODEL = 768, N_STATE = 16.
// y[row,d] = x[row,d] * softplus((x@W1+b1)[row,d]) * dot(x@W2+b2, x@W3+b3)[row]
// (dA*h0 term is identically zero; A unused.)
// Ledger: ~44-62 us harness fills per iter (fixed). R10: register-pipelined
// direct-from-global GEMM loses 2x -> LDS+barrier k-loop is the structure.
// R11: fold s into the gemm (row-local). R12 (this round): fuse x->bf16 into
// the gemm's A-staging (reg-stage fp32 -> v_cvt_pk -> ds_write_b128, same
// XOR-swizzled layout); prep shrinks to W-prep only (608 blocks); epilogue
// reads x fp32 (L2-hot k-slice) instead of xb. Deletes the 38 MB streaming
// pass + the 12.6 MB xb round-trip.

#define M_ROWS 8192
#define DM 768
#define NS 16

typedef short bf16x8 __attribute__((ext_vector_type(8)));
typedef unsigned short u16x8 __attribute__((ext_vector_type(8)));
typedef float f32x4 __attribute__((ext_vector_type(4)));

__device__ __forceinline__ unsigned short f2bf(float f) {
    union { float f; unsigned u; } v; v.f = f;
    unsigned r = v.u + 0x7FFF + ((v.u >> 16) & 1);   // RNE
    return (unsigned short)(r >> 16);
}
// compiler lowers scalar casts to packed v_cvt_pk_bf16_f32 (RNE) on gfx950
__device__ __forceinline__ unsigned short cvtbf(float f) {
    __hip_bfloat16 h = __float2bfloat16(f);
    return *reinterpret_cast<unsigned short*>(&h);
}
__device__ __forceinline__ void async16(const void* g, void* l) {
    __builtin_amdgcn_global_load_lds(
        (const __attribute__((address_space(1))) void*)g,
        (__attribute__((address_space(3))) void*)l,
        16, 0, 0);
}
// branchless stable softplus: max(v,0) + log(1+exp(-|v|)); HW exp/log.
__device__ __forceinline__ float softplus_fast(float v) {
    return fmaxf(v, 0.f) + __logf(1.f + __expf(-fabsf(v)));
}

// ---- kernel 1: W-prep only (608 blocks) ---------------------------------
// bid [0,32):   w23t build (bf16 n-major, pair-interleaved W2/W3 cols).
// bid [32,608): W1 [k][n] fp32 -> w1t [n][k] bf16 (32x32 LDS tiles).
__global__ __launch_bounds__(256) void prep_kernel(
    const float* __restrict__ W1,
    const float* __restrict__ W2,
    const float* __restrict__ W3,
    unsigned short* __restrict__ w1t,
    unsigned short* __restrict__ w23t)
{
    __shared__ float tile[32][33];
    const int bid = blockIdx.x;
    const int tid = threadIdx.x;
    if (bid < 32) {
        const int n = bid, i = n >> 1;
        const float* src = (n & 1) ? W3 : W2;
        #pragma unroll
        for (int e = 0; e < 3; ++e) {
            int k = e * 256 + tid;
            w23t[n * DM + k] = f2bf(src[k * NS + i]);
        }
    } else {
        const int b2i = bid - 32;                // 0..575
        const int n0 = (b2i % 24) * 32, k0 = (b2i / 24) * 32;
        const int tx = tid & 31, ty = tid >> 5;  // 32 x 8
        #pragma unroll
        for (int i = 0; i < 4; ++i) {
            int k = ty + i * 8;
            tile[k][tx] = W1[(k0 + k) * DM + n0 + tx];
        }
        __syncthreads();
        #pragma unroll
        for (int i = 0; i < 4; ++i) {
            int n = ty + i * 8;
            w1t[(n0 + n) * DM + k0 + tx] = f2bf(tile[tx][n]);
        }
    }
}

// ---- kernel 2: fused cvt + GEMM + integrated s + softplus epilogue ------
// R9-exact k-loop structure (single-buffered LDS, 2 barriers/step, 256 thr,
// 4 waves 2x2, 128x64 tile, BK=64, XCD swizzle). A-tile is now staged from
// x fp32: 8x global_load_dwordx4 -> 32 cvt (packed) -> 4x ds_write_b128 per
// thread, into the SAME XOR-swizzled LDS layout the fragment reads expect.
// B (w1t) and W23 still stage via global_load_lds (bf16, prep'd once).
// P = xb_tile @ w23^T per block; pair-product partials reduce via the
// verified R4 shfl algebra, cross-wn combine through 1 KB LDS.
__global__ __launch_bounds__(256) void gemm_fused_kernel(
    const float* __restrict__ x,              // [8192][768] fp32
    const unsigned short* __restrict__ w1t,   // [768][768] bf16, n-major
    const unsigned short* __restrict__ w23t,  // [32][768] bf16, pair-interleaved
    const float* __restrict__ b1,
    const float* __restrict__ b2, const float* __restrict__ b3,
    float* __restrict__ y)
{
    __shared__ unsigned short Al[128 * 64];   // 16 KB
    __shared__ unsigned short Bl[64 * 64];    //  8 KB
    __shared__ unsigned short Wl[32 * 64];    //  4 KB
    __shared__ float spart[2][128];           //  1 KB
    const int b = blockIdx.x;
    const int c = b & 7, j = b >> 3;          // j in [0,96)
    const int m0 = (c * 8 + j / 12) * 128;
    const int n0 = (j % 12) * 64;
    const int tid  = threadIdx.x;
    const int lane = tid & 63;
    const int wave = tid >> 6;
    const int wm = wave >> 1, wn = wave & 1;
    const int l15 = lane & 15, quad = lane >> 4;

    f32x4 acc[4][2];
    f32x4 accP[4];
    #pragma unroll
    for (int i = 0; i < 4; ++i) {
        accP[i] = (f32x4){0.f, 0.f, 0.f, 0.f};
        #pragma unroll
        for (int jj = 0; jj < 2; ++jj)
            acc[i][jj] = (f32x4){0.f, 0.f, 0.f, 0.f};
    }

    for (int k0 = 0; k0 < DM; k0 += 64) {
        // A: issue 8 dwordx4 fp32 loads first (latency head start)
        float4 va[8];
        #pragma unroll
        for (int i = 0; i < 4; ++i) {
            int ch = tid + i * 256;
            int r = ch >> 3, jg = (ch & 7) ^ (r & 7);
            const float4* src = (const float4*)(x + (m0 + r) * DM + k0 + jg * 8);
            va[2 * i]     = src[0];
            va[2 * i + 1] = src[1];
        }
        #pragma unroll
        for (int i = 0; i < 2; ++i) {         // B: 512 chunks, stays in flight
            int ch = tid + i * 256;
            int r = ch >> 3, jg = (ch & 7) ^ (r & 7);
            async16(w1t + (n0 + r) * DM + k0 + jg * 8, Bl + ch * 8);
        }
        {                                      // W23: 256 chunks
            int ch = tid;
            int r = ch >> 3, jg = (ch & 7) ^ (r & 7);
            async16(w23t + r * DM + k0 + jg * 8, Wl + ch * 8);
        }
        // convert + write A (same swizzled layout: lds chunk ch holds
        // row r = ch>>3, col-group (ch&7)^(r&7) — matched to the loads above)
        #pragma unroll
        for (int i = 0; i < 4; ++i) {
            int ch = tid + i * 256;
            float4 a = va[2 * i], bb = va[2 * i + 1];
            u16x8 o;
            o[0] = cvtbf(a.x);  o[1] = cvtbf(a.y);
            o[2] = cvtbf(a.z);  o[3] = cvtbf(a.w);
            o[4] = cvtbf(bb.x); o[5] = cvtbf(bb.y);
            o[6] = cvtbf(bb.z); o[7] = cvtbf(bb.w);
            *(u16x8*)(Al + ch * 8) = o;
        }
        __syncthreads();

        #pragma unroll
        for (int kk = 0; kk < 2; ++kk) {
            bf16x8 bfr[2], wfr;
            #pragma unroll
            for (int jj = 0; jj < 2; ++jj) {
                int rb = wn * 32 + jj * 16 + l15;
                int jb = (kk * 4 + quad) ^ (rb & 7);
                bfr[jj] = *(const bf16x8*)(Bl + rb * 64 + jb * 8);
            }
            {
                int rw = wn * 16 + l15;
                int jw = (kk * 4 + quad) ^ (rw & 7);
                wfr = *(const bf16x8*)(Wl + rw * 64 + jw * 8);
            }
            #pragma unroll
            for (int i = 0; i < 4; ++i) {
                int rr = wm * 64 + i * 16 + l15;
                int ja = (kk * 4 + quad) ^ (rr & 7);
                bf16x8 af = *(const bf16x8*)(Al + rr * 64 + ja * 8);
                #pragma unroll
                for (int jj = 0; jj < 2; ++jj)
                    acc[i][jj] = __builtin_amdgcn_mfma_f32_16x16x32_bf16(
                        af, bfr[jj], acc[i][jj], 0, 0, 0);
                accP[i] = __builtin_amdgcn_mfma_f32_16x16x32_bf16(
                    af, wfr, accP[i], 0, 0, 0);
            }
        }
        __syncthreads();
    }

    // ---- s partials: this wave owns pairs p = wn*8 + (l15>>1) ----
    {
        const int p = wn * 8 + (l15 >> 1);
        const float bB = b2[p], bC = b3[p];
        #pragma unroll
        for (int i = 0; i < 4; ++i) {
            float sacc[4];
            #pragma unroll
            for (int r = 0; r < 4; ++r) {
                float v = accP[i][r];
                float pv = __shfl_xor(v, 1, 64);
                sacc[r] = (l15 & 1) ? (pv + bB) * (v + bC)
                                    : (v + bB) * (pv + bC);
                sacc[r] += __shfl_xor(sacc[r], 1, 64);
                sacc[r] += __shfl_xor(sacc[r], 2, 64);
                sacc[r] += __shfl_xor(sacc[r], 4, 64);
                sacc[r] += __shfl_xor(sacc[r], 8, 64);
            }
            if (l15 == 0) {
                #pragma unroll
                for (int r = 0; r < 4; ++r)
                    spart[wn][wm * 64 + i * 16 + quad * 4 + r] = 0.5f * sacc[r];
            }
        }
    }
    __syncthreads();

    // ---- epilogue: C/D layout col = lane&15, row = quad*4 + reg ----
    // xv read from x fp32 (L2-hot: this block staged the k-slice == n-range)
    #pragma unroll
    for (int i = 0; i < 4; ++i) {
        const int rl = wm * 64 + i * 16 + quad * 4;   // local row base
        const int rowbase = m0 + rl;
        float sv4[4];
        #pragma unroll
        for (int r = 0; r < 4; ++r)
            sv4[r] = spart[0][rl + r] + spart[1][rl + r];
        #pragma unroll
        for (int jj = 0; jj < 2; ++jj) {
            int gcol = n0 + wn * 32 + jj * 16 + l15;
            float bias = b1[gcol];
            #pragma unroll
            for (int r = 0; r < 4; ++r) {
                int grow = rowbase + r;
                float v = acc[i][jj][r] + bias;
                float sp = softplus_fast(v);
                float xv = x[grow * DM + gcol];
                y[grow * DM + gcol] = xv * sp * sv4[r];
            }
        }
    }
}

extern "C" void kernel_launch(void* const* d_in, const int* in_sizes, int n_in,
                              void* d_out, int out_size, void* d_ws, size_t ws_size,
                              hipStream_t stream) {
    const float* x  = (const float*)d_in[0];
    const float* W1 = (const float*)d_in[1];
    const float* b1 = (const float*)d_in[2];
    const float* W2 = (const float*)d_in[3];
    const float* b2 = (const float*)d_in[4];
    const float* W3 = (const float*)d_in[5];
    const float* b3 = (const float*)d_in[6];
    // d_in[7] = A : unused (multiplied by h0 == 0 in the reference)
    float* y = (float*)d_out;

    unsigned short* w1t  = (unsigned short*)d_ws;                     // 1,179,648 B
    unsigned short* w23t = (unsigned short*)((char*)d_ws + 1179648);  //    49,152 B

    prep_kernel<<<608, 256, 0, stream>>>(W1, W2, W3, w1t, w23t);
    gemm_fused_kernel<<<768, 256, 0, stream>>>(x, w1t, w23t, b1, b2, b3, y);
}